// Round 3
// baseline (1270.370 us; speedup 1.0000x reference)
//
#include <hip/hip_runtime.h>

#define B_ 8192
#define T_ 256
#define H_ 128
#define ROWS 16
#define NTH 512

typedef __attribute__((ext_vector_type(4))) float f32x4;
typedef __attribute__((ext_vector_type(4))) short short4_t;
typedef __attribute__((ext_vector_type(8))) short short8_t;
typedef __attribute__((ext_vector_type(8))) _Float16 half8;
typedef __attribute__((ext_vector_type(2))) _Float16 half2_t;
typedef __attribute__((ext_vector_type(2))) unsigned int uint2_t;
typedef __attribute__((ext_vector_type(4))) unsigned int uint4_t;

__device__ __forceinline__ float fast_exp(float x) {
    return __builtin_amdgcn_exp2f(x * 1.4426950408889634f);
}
__device__ __forceinline__ float sigm(float x) {
    return __builtin_amdgcn_rcpf(1.0f + fast_exp(-x));
}
__device__ __forceinline__ float tanh_f(float x) {
    return 1.0f - 2.0f * __builtin_amdgcn_rcpf(1.0f + fast_exp(2.0f * x));
}
__device__ __forceinline__ short h16bits(float v) {
    return __builtin_bit_cast(short, (_Float16)v);
}
__device__ __forceinline__ float h16f(short s) {
    return (float)__builtin_bit_cast(_Float16, s);
}
__device__ __forceinline__ unsigned pk2(float lo, float hi) {
    return __builtin_bit_cast(unsigned, __builtin_amdgcn_cvt_pkrtz(lo, hi));
}
__device__ __forceinline__ half2_t h2(unsigned u) {
    return __builtin_bit_cast(half2_t, u);
}
__device__ __forceinline__ unsigned pkadd(unsigned a, unsigned b) {
    return __builtin_bit_cast(unsigned, (half2_t)(h2(a) + h2(b)));
}
// segmented (16-lane rows) sum of a packed f16 pair; valid in lane 16g+15
__device__ __forceinline__ unsigned red16_pk(unsigned v) {
    v = pkadd(v, (unsigned)__builtin_amdgcn_update_dpp(0, (int)v, 0x111, 0xf, 0xf, true));
    v = pkadd(v, (unsigned)__builtin_amdgcn_update_dpp(0, (int)v, 0x112, 0xf, 0xf, true));
    v = pkadd(v, (unsigned)__builtin_amdgcn_update_dpp(0, (int)v, 0x114, 0xf, 0xf, true));
    v = pkadd(v, (unsigned)__builtin_amdgcn_update_dpp(0, (int)v, 0x118, 0xf, 0xf, true));
    return v;
}

// WG = 16 batch rows, 8 waves, wave w owns H-cols [16w,16w+16).
// Two blocks per CU (grid 512) for latency hiding; regs capped at 128/wave.
// K-chunks: 0..3 feat (W_ih), 4..7 h (W_hh); mfma_f32_16x16x32_f16.
// A-frag layout: elem (row i, k) -> chunk[(i + 16*((k&31)>>3))*8 + (k&7)]
__global__ __launch_bounds__(NTH, 4) void brits_kernel(
    const float* __restrict__ x_seq, const float* __restrict__ m_seq,
    const float* __restrict__ Wc_w,  const float* __restrict__ Wc_b,
    const float* __restrict__ Wx_w,  const float* __restrict__ Wx_b,
    const float* __restrict__ W_ih,  const float* __restrict__ W_hh,
    const float* __restrict__ b_ih,  const float* __restrict__ b_hh,
    const float* __restrict__ out_w, const float* __restrict__ out_b,
    float* __restrict__ out)
{
    __shared__ __align__(16) short feat_s[4][512];       // 4 KiB
    __shared__ __align__(16) short h_s[2][4][512];       // 8 KiB, double-buffered
    __shared__ __align__(16) short x_all[T_][ROWS];      // 8 KiB f16 transposed
    __shared__ __align__(16) short m_all[T_][ROWS];      // 8 KiB
    __shared__ __align__(16) short comp_sh[ROWS][264];   // 8.25 KiB
    __shared__ __align__(16) short pred_sh[ROWS][264];   // 8.25 KiB
    __shared__ __align__(16) unsigned part_cp[ROWS][8];  // packed (c,p) partials
    __shared__ __align__(16) float wx_s[H_];
    __shared__ __align__(16) float bx_s[H_];

    const int tid  = threadIdx.x;
    const int lane = tid & 63;
    const int wv   = tid >> 6;
    const int kg   = lane >> 4;
    const int ln16 = lane & 15;
    const int rb   = kg * 4;
    const long b0  = (long)blockIdx.x * ROWS;

    const int rowA = tid & 15;     // phase-A row
    const int kqA  = tid >> 4;     // phase-A k-quad 0..31

    const float cb = Wc_b[0];
    const float ob = out_b[0];

    const int cH = wv * 16 + ln16;
    const int cR = cH, cZ = cH + 128, cN = cH + 256;

    // packed per-lane constants (f16 pairs)
    const unsigned bRZ  = pk2(b_ih[cR] + b_hh[cR], b_ih[cZ] + b_hh[cZ]);
    const unsigned WmRZ = pk2(W_ih[cR * 129 + 128], W_ih[cZ * 129 + 128]);
    const unsigned bNN  = pk2(b_ih[cN], b_hh[cN]);
    const unsigned WmN0 = pk2(W_ih[cN * 129 + 128], 0.0f);
    const float wcc = Wc_w[cH];
    const float owc = out_w[cH];

    // ---- weight B-fragments (f16) into registers, held across t-loop ----
    half8 wr[8], wz[8], wn[8];
#pragma unroll
    for (int kc = 0; kc < 8; ++kc) {
        const float *pr, *pz, *pn;
        if (kc < 4) {
            const int off = kc * 32 + kg * 8;
            pr = W_ih + cR * 129 + off;
            pz = W_ih + cZ * 129 + off;
            pn = W_ih + cN * 129 + off;
        } else {
            const int off = (kc - 4) * 32 + kg * 8;
            pr = W_hh + cR * 128 + off;
            pz = W_hh + cZ * 128 + off;
            pn = W_hh + cN * 128 + off;
        }
#pragma unroll
        for (int e = 0; e < 8; ++e) {
            wr[kc][e] = (_Float16)pr[e];
            wz[kc][e] = (_Float16)pz[e];
            wn[kc][e] = (_Float16)pn[e];
        }
    }

    // ---- one-time LDS init ----
    {   // x/m panel: coalesced read, transposed f16 store
        const int prow = tid >> 5;          // 0..15
        const int pc0  = (tid & 31) * 8;    // 0..248
        const float* xp = x_seq + (b0 + prow) * T_ + pc0;
        const float* mp = m_seq + (b0 + prow) * T_ + pc0;
#pragma unroll
        for (int i = 0; i < 2; ++i) {
            f32x4 xv = *(const f32x4*)(xp + 4 * i);
            f32x4 mv = *(const f32x4*)(mp + 4 * i);
#pragma unroll
            for (int j = 0; j < 4; ++j) {
                x_all[pc0 + 4 * i + j][prow] = h16bits(xv[j]);
                m_all[pc0 + 4 * i + j][prow] = h16bits(mv[j]);
            }
        }
    }
    if (tid < H_) { wx_s[tid] = Wx_w[tid]; bx_s[tid] = Wx_b[tid]; }
    {   // zero both h buffers (4096 shorts)
        short8_t z8 = {0, 0, 0, 0, 0, 0, 0, 0};
        *(short8_t*)((short*)h_s + tid * 8) = z8;
    }
    if (tid < ROWS * 8) ((unsigned*)part_cp)[tid] = 0u;

    // h carried as packed f16 (consistent with what the GEMM consumes)
    unsigned hp0 = 0u, hp1 = 0u;
    __syncthreads();

    // ---- main recurrence: 2 barriers/step, zero global traffic ----
    for (int t = 0; t < T_; ++t) {
        const int pb = t & 1, nb = pb ^ 1;

        // phase A: combine packed (c,p) partials; c_t, pred[t-1], feat frags
        uint4_t u0 = *(const uint4_t*)&part_cp[rowA][0];
        uint4_t u1 = *(const uint4_t*)&part_cp[rowA][4];
        unsigned sacc = pkadd(pkadd(pkadd(u0[0], u0[1]), pkadd(u0[2], u0[3])),
                              pkadd(pkadd(u1[0], u1[1]), pkadd(u1[2], u1[3])));
        const half2_t sv = h2(sacc);
        const float c_t = tanh_f((float)sv[0] + cb);
        if (kqA == 0) comp_sh[rowA][t] = h16bits(c_t);
        if (kqA == 1 && t > 0) pred_sh[rowA][t - 1] = h16bits((float)sv[1] + ob);

        const float xv = h16f(x_all[t][rowA]);
        const float mv = h16f(m_all[t][rowA]);
        const float xi = (mv != 0.0f) ? xv : c_t;
        {
            const int k = kqA * 4;
            f32x4 wx4 = *(const f32x4*)&wx_s[k];
            f32x4 bx4 = *(const f32x4*)&bx_s[k];
            float f0 = fmaxf(xi * wx4[0] + bx4[0], 0.0f);
            float f1 = fmaxf(xi * wx4[1] + bx4[1], 0.0f);
            float f2 = fmaxf(xi * wx4[2] + bx4[2], 0.0f);
            float f3 = fmaxf(xi * wx4[3] + bx4[3], 0.0f);
            uint2_t pk; pk[0] = pk2(f0, f1); pk[1] = pk2(f2, f3);
            const int o = (kqA >> 1) & 3, j = (kqA & 1) * 4;
            *(uint2_t*)&feat_s[kqA >> 3][(rowA + 16 * o) * 8 + j] = pk;
        }

        // acc init from packed consts (m in {0,1} exact in f16)
        short4_t m4 = *(const short4_t*)&m_all[t][rb];
        f32x4 aR, aZ, aNi, aNh;
#pragma unroll
        for (int e = 0; e < 4; ++e) {
            unsigned mu = (unsigned)(unsigned short)m4[e];
            mu |= mu << 16;
            half2_t rz = h2(mu) * h2(WmRZ) + h2(bRZ);
            half2_t nn = h2(mu) * h2(WmN0) + h2(bNN);
            aR[e] = (float)rz[0]; aZ[e] = (float)rz[1];
            aNi[e] = (float)nn[0]; aNh[e] = (float)nn[1];
        }
        __syncthreads();  // B1: feat frags visible

        // gate GEMM: 4 feat chunks + 4 h chunks, 3 gates each
#pragma unroll
        for (int kc = 0; kc < 4; ++kc) {
            half8 a = __builtin_bit_cast(half8, *(const short8_t*)&feat_s[kc][lane * 8]);
            aR  = __builtin_amdgcn_mfma_f32_16x16x32_f16(a, wr[kc], aR, 0, 0, 0);
            aZ  = __builtin_amdgcn_mfma_f32_16x16x32_f16(a, wz[kc], aZ, 0, 0, 0);
            aNi = __builtin_amdgcn_mfma_f32_16x16x32_f16(a, wn[kc], aNi, 0, 0, 0);
        }
#pragma unroll
        for (int kc = 0; kc < 4; ++kc) {
            half8 a = __builtin_bit_cast(half8, *(const short8_t*)&h_s[pb][kc][lane * 8]);
            aR  = __builtin_amdgcn_mfma_f32_16x16x32_f16(a, wr[4 + kc], aR, 0, 0, 0);
            aZ  = __builtin_amdgcn_mfma_f32_16x16x32_f16(a, wz[4 + kc], aZ, 0, 0, 0);
            aNh = __builtin_amdgcn_mfma_f32_16x16x32_f16(a, wn[4 + kc], aNh, 0, 0, 0);
        }

        // gates + h update
        f32x4 hn;
        {
            const float h0 = (float)h2(hp0)[0], h1 = (float)h2(hp0)[1];
            const float h2v = (float)h2(hp1)[0], h3 = (float)h2(hp1)[1];
            float r, z, n;
            r = sigm(aR[0]); z = sigm(aZ[0]); n = tanh_f(aNi[0] + r * aNh[0]);
            hn[0] = z * (h0 - n) + n;
            r = sigm(aR[1]); z = sigm(aZ[1]); n = tanh_f(aNi[1] + r * aNh[1]);
            hn[1] = z * (h1 - n) + n;
            r = sigm(aR[2]); z = sigm(aZ[2]); n = tanh_f(aNi[2] + r * aNh[2]);
            hn[2] = z * (h2v - n) + n;
            r = sigm(aR[3]); z = sigm(aZ[3]); n = tanh_f(aNi[3] + r * aNh[3]);
            hn[3] = z * (h3 - n) + n;
        }
        hp0 = pk2(hn[0], hn[1]);
        hp1 = pk2(hn[2], hn[3]);

        // write h frags (f16, exactly the packed values) into next buffer
        {
            short* hdst = &h_s[nb][cH >> 5][((cH & 31) >> 3) * 128 + (cH & 7)];
            hdst[(rb + 0) * 8] = (short)(hp0 & 0xffffu);
            hdst[(rb + 1) * 8] = (short)(hp0 >> 16);
            hdst[(rb + 2) * 8] = (short)(hp1 & 0xffffu);
            hdst[(rb + 3) * 8] = (short)(hp1 >> 16);
        }
        // fused (c,p) packed segmented reduction
#pragma unroll
        for (int e = 0; e < 4; ++e) {
            unsigned v = red16_pk(pk2(hn[e] * wcc, hn[e] * owc));
            if (ln16 == 15) part_cp[rb + e][wv] = v;
        }
        __syncthreads();  // B2
    }

    // final pred from last step's partials
    {
        uint4_t u0 = *(const uint4_t*)&part_cp[rowA][0];
        uint4_t u1 = *(const uint4_t*)&part_cp[rowA][4];
        unsigned sacc = pkadd(pkadd(pkadd(u0[0], u0[1]), pkadd(u0[2], u0[3])),
                              pkadd(pkadd(u1[0], u1[1]), pkadd(u1[2], u1[3])));
        if (kqA == 1) pred_sh[rowA][T_ - 1] = h16bits((float)h2(sacc)[1] + ob);
    }
    __syncthreads();

    // coalesced output: preds [0, B*T), comps [B*T, 2*B*T)
    {
        const int orow = tid >> 5;
        const int oc   = (tid & 31) * 8;
        short8_t pv = *(const short8_t*)&pred_sh[orow][oc];
        float* gp = out + (b0 + orow) * T_ + oc;
#pragma unroll
        for (int i = 0; i < 2; ++i) {
            f32x4 o;
            o[0] = h16f(pv[i * 4 + 0]); o[1] = h16f(pv[i * 4 + 1]);
            o[2] = h16f(pv[i * 4 + 2]); o[3] = h16f(pv[i * 4 + 3]);
            *(f32x4*)(gp + 4 * i) = o;
        }
        short8_t cv = *(const short8_t*)&comp_sh[orow][oc];
        float* gc = out + (long)B_ * T_ + (b0 + orow) * T_ + oc;
#pragma unroll
        for (int i = 0; i < 2; ++i) {
            f32x4 o;
            o[0] = h16f(cv[i * 4 + 0]); o[1] = h16f(cv[i * 4 + 1]);
            o[2] = h16f(cv[i * 4 + 2]); o[3] = h16f(cv[i * 4 + 3]);
            *(f32x4*)(gc + 4 * i) = o;
        }
    }
}

extern "C" void kernel_launch(void* const* d_in, const int* in_sizes, int n_in,
                              void* d_out, int out_size, void* d_ws, size_t ws_size,
                              hipStream_t stream) {
    const float* x_seq = (const float*)d_in[0];
    const float* m_seq = (const float*)d_in[1];
    const float* Wc_w  = (const float*)d_in[2];
    const float* Wc_b  = (const float*)d_in[3];
    const float* Wx_w  = (const float*)d_in[4];
    const float* Wx_b  = (const float*)d_in[5];
    const float* W_ih  = (const float*)d_in[6];
    const float* W_hh  = (const float*)d_in[7];
    const float* b_ih  = (const float*)d_in[8];
    const float* b_hh  = (const float*)d_in[9];
    const float* out_w = (const float*)d_in[10];
    const float* out_b = (const float*)d_in[11];
    float* out = (float*)d_out;

    dim3 grid(B_ / ROWS);   // 512 workgroups -> 2 blocks per CU
    dim3 block(NTH);
    brits_kernel<<<grid, block, 0, stream>>>(x_seq, m_seq, Wc_w, Wc_b, Wx_w, Wx_b,
                                             W_ih, W_hh, b_ih, b_hh, out_w, out_b, out);
}

// Round 5
// 682.261 us; speedup vs baseline: 1.8620x; 1.8620x over previous
//
#include <hip/hip_runtime.h>

#define B_ 8192
#define T_ 256
#define H_ 128
#define ROWS 32
#define NTH 512

typedef __attribute__((ext_vector_type(4))) float f32x4;
typedef __attribute__((ext_vector_type(4))) short short4_t;
typedef __attribute__((ext_vector_type(8))) short short8_t;
typedef __attribute__((ext_vector_type(8))) _Float16 half8;
typedef __attribute__((ext_vector_type(2))) _Float16 half2_t;
typedef __attribute__((ext_vector_type(4))) unsigned int uint4_t;

__device__ __forceinline__ float fast_exp(float x) {
    return __builtin_amdgcn_exp2f(x * 1.4426950408889634f);
}
__device__ __forceinline__ float sigm(float x) {
    return __builtin_amdgcn_rcpf(1.0f + fast_exp(-x));
}
__device__ __forceinline__ float tanh_f(float x) {
    return 1.0f - 2.0f * __builtin_amdgcn_rcpf(1.0f + fast_exp(2.0f * x));
}
__device__ __forceinline__ short h16bits(float v) {
    return __builtin_bit_cast(short, (_Float16)v);
}
__device__ __forceinline__ float h16f(short s) {
    return (float)__builtin_bit_cast(_Float16, s);
}
__device__ __forceinline__ unsigned pk2(float lo, float hi) {
    return __builtin_bit_cast(unsigned, __builtin_amdgcn_cvt_pkrtz(lo, hi));
}
__device__ __forceinline__ half2_t h2(unsigned u) {
    return __builtin_bit_cast(half2_t, u);
}
__device__ __forceinline__ unsigned pkadd(unsigned a, unsigned b) {
    return __builtin_bit_cast(unsigned, (half2_t)(h2(a) + h2(b)));
}
// segmented (16-lane rows) sum of packed f16 pair; valid in lane 16g+15
__device__ __forceinline__ unsigned red16_pk(unsigned v) {
    v = pkadd(v, (unsigned)__builtin_amdgcn_update_dpp(0, (int)v, 0x111, 0xf, 0xf, true));
    v = pkadd(v, (unsigned)__builtin_amdgcn_update_dpp(0, (int)v, 0x112, 0xf, 0xf, true));
    v = pkadd(v, (unsigned)__builtin_amdgcn_update_dpp(0, (int)v, 0x114, 0xf, 0xf, true));
    v = pkadd(v, (unsigned)__builtin_amdgcn_update_dpp(0, (int)v, 0x118, 0xf, 0xf, true));
    return v;
}

// WG = 32 rows (2 tiles of 16), 8 waves, wave w owns H-cols [16w,16w+16).
// ONE barrier per step: feat A-frags built redundantly in registers per lane
// (needs only c_t + per-lane Wx/bx consts); only h-frags and c/p partials go
// through LDS (both double-buffered). h-chunk MFMAs issue right after the
// barrier and overlap the partial-combine + feat VALU.
// A-frag layout: elem (row i, k) -> chunk[(i + 16*((k&31)>>3))*8 + (k&7)]
__global__ __launch_bounds__(NTH, 2) void brits_kernel(
    const float* __restrict__ x_seq, const float* __restrict__ m_seq,
    const float* __restrict__ Wc_w,  const float* __restrict__ Wc_b,
    const float* __restrict__ Wx_w,  const float* __restrict__ Wx_b,
    const float* __restrict__ W_ih,  const float* __restrict__ W_hh,
    const float* __restrict__ b_ih,  const float* __restrict__ b_hh,
    const float* __restrict__ out_w, const float* __restrict__ out_b,
    float* __restrict__ out)
{
    __shared__ __align__(16) short h_s[2][2][4][512];     // 16 KiB dbuf h frags
    __shared__ __align__(16) short x_all[T_][ROWS];       // 16 KiB f16 transposed
    __shared__ __align__(16) short m_all[T_][ROWS];       // 16 KiB
    __shared__ __align__(16) short comp_sh[ROWS][264];    // 16.5 KiB
    __shared__ __align__(16) short pred_sh[ROWS][264];    // 16.5 KiB
    __shared__ __align__(16) unsigned part_cp[2][ROWS][12]; // dbuf packed (c,p), padded

    const int tid  = threadIdx.x;
    const int lane = tid & 63;
    const int wv   = tid >> 6;
    const int kg   = lane >> 4;
    const int ln16 = lane & 15;
    const int rb   = kg * 4;
    const int rA   = lane & 15;        // per-lane feat row (tile0); tile1 = 16+rA
    const long b0  = (long)blockIdx.x * ROWS;

    const float cb = Wc_b[0];
    const float ob = out_b[0];

    const int cH = wv * 16 + ln16;
    const int cR = cH, cZ = cH + 128, cN = cH + 256;

    const unsigned bRZ  = pk2(b_ih[cR] + b_hh[cR], b_ih[cZ] + b_hh[cZ]);
    const unsigned WmRZ = pk2(W_ih[cR * 129 + 128], W_ih[cZ * 129 + 128]);
    const unsigned bNN  = pk2(b_ih[cN], b_hh[cN]);
    const unsigned WmN0 = pk2(W_ih[cN * 129 + 128], 0.0f);
    const float wcc = Wc_w[cH];
    const float owc = out_w[cH];

    // ---- weight B-fragments (f16) in registers across the t-loop ----
    half8 wr[8], wz[8], wn[8];
#pragma unroll
    for (int kc = 0; kc < 8; ++kc) {
        const float *pr, *pz, *pn;
        if (kc < 4) {
            const int off = kc * 32 + kg * 8;
            pr = W_ih + cR * 129 + off;
            pz = W_ih + cZ * 129 + off;
            pn = W_ih + cN * 129 + off;
        } else {
            const int off = (kc - 4) * 32 + kg * 8;
            pr = W_hh + cR * 128 + off;
            pz = W_hh + cZ * 128 + off;
            pn = W_hh + cN * 128 + off;
        }
#pragma unroll
        for (int e = 0; e < 8; ++e) {
            wr[kc][e] = (_Float16)pr[e];
            wz[kc][e] = (_Float16)pz[e];
            wn[kc][e] = (_Float16)pn[e];
        }
    }

    // per-lane Wx/bx slices, packed f16: k = c*32 + kg*8 + 2p (+1)
    unsigned wxp[16], bxp[16];
#pragma unroll
    for (int c = 0; c < 4; ++c)
#pragma unroll
        for (int p = 0; p < 4; ++p) {
            const int k = c * 32 + kg * 8 + 2 * p;
            wxp[c * 4 + p] = pk2(Wx_w[k], Wx_w[k + 1]);
            bxp[c * 4 + p] = pk2(Wx_b[k], Wx_b[k + 1]);
        }

    // ---- one-time LDS init ----
    {   // x/m panel: coalesced read, transposed f16 store
        const int prow = tid >> 4;          // 0..31
        const int ptb  = (tid & 15) * 16;   // 16 t-values per thread
        const float* xp = x_seq + (b0 + prow) * T_ + ptb;
        const float* mp = m_seq + (b0 + prow) * T_ + ptb;
#pragma unroll
        for (int i = 0; i < 4; ++i) {
            f32x4 xv = *(const f32x4*)(xp + 4 * i);
            f32x4 mv = *(const f32x4*)(mp + 4 * i);
#pragma unroll
            for (int j = 0; j < 4; ++j) {
                x_all[ptb + 4 * i + j][prow] = h16bits(xv[j]);
                m_all[ptb + 4 * i + j][prow] = h16bits(mv[j]);
            }
        }
    }
    {   // zero h buffer 0 (4096 shorts)
        short8_t z8 = {0, 0, 0, 0, 0, 0, 0, 0};
        *(short8_t*)((short*)h_s + tid * 8) = z8;
    }
    if (tid < ROWS * 12) ((unsigned*)part_cp)[tid] = 0u;   // zero partial buf 0

    unsigned hpa0 = 0u, hpa1 = 0u, hpb0 = 0u, hpb1 = 0u;   // h carry (f16 pk)
    __syncthreads();

    // ---- main recurrence: ONE barrier per step ----
    for (int t = 0; t < T_; ++t) {
        const int pb = t & 1, nb = pb ^ 1;

        // issue partial reads early (LDS latency cover)
        uint4_t u0a = *(const uint4_t*)&part_cp[pb][rA][0];
        uint4_t u1a = *(const uint4_t*)&part_cp[pb][rA][4];
        uint4_t u0b = *(const uint4_t*)&part_cp[pb][16 + rA][0];
        uint4_t u1b = *(const uint4_t*)&part_cp[pb][16 + rA][4];

        // acc init from packed consts (m exact in f16)
        short4_t m4a = *(const short4_t*)&m_all[t][rb];
        short4_t m4b = *(const short4_t*)&m_all[t][16 + rb];
        f32x4 aR0, aZ0, aNi0, aNh0, aR1, aZ1, aNi1, aNh1;
#pragma unroll
        for (int e = 0; e < 4; ++e) {
            unsigned mu0 = (unsigned)(unsigned short)m4a[e]; mu0 |= mu0 << 16;
            unsigned mu1 = (unsigned)(unsigned short)m4b[e]; mu1 |= mu1 << 16;
            half2_t rz0 = h2(mu0) * h2(WmRZ) + h2(bRZ);
            half2_t nn0 = h2(mu0) * h2(WmN0) + h2(bNN);
            half2_t rz1 = h2(mu1) * h2(WmRZ) + h2(bRZ);
            half2_t nn1 = h2(mu1) * h2(WmN0) + h2(bNN);
            aR0[e] = (float)rz0[0]; aZ0[e] = (float)rz0[1];
            aNi0[e] = (float)nn0[0]; aNh0[e] = (float)nn0[1];
            aR1[e] = (float)rz1[0]; aZ1[e] = (float)rz1[1];
            aNi1[e] = (float)nn1[0]; aNh1[e] = (float)nn1[1];
        }

        // h-chunk MFMAs first (independent of c_t / feat)
#pragma unroll
        for (int kc = 0; kc < 4; ++kc) {
            half8 a0 = __builtin_bit_cast(half8, *(const short8_t*)&h_s[pb][0][kc][lane * 8]);
            half8 a1 = __builtin_bit_cast(half8, *(const short8_t*)&h_s[pb][1][kc][lane * 8]);
            aR0  = __builtin_amdgcn_mfma_f32_16x16x32_f16(a0, wr[4 + kc], aR0, 0, 0, 0);
            aZ0  = __builtin_amdgcn_mfma_f32_16x16x32_f16(a0, wz[4 + kc], aZ0, 0, 0, 0);
            aNh0 = __builtin_amdgcn_mfma_f32_16x16x32_f16(a0, wn[4 + kc], aNh0, 0, 0, 0);
            aR1  = __builtin_amdgcn_mfma_f32_16x16x32_f16(a1, wr[4 + kc], aR1, 0, 0, 0);
            aZ1  = __builtin_amdgcn_mfma_f32_16x16x32_f16(a1, wz[4 + kc], aZ1, 0, 0, 0);
            aNh1 = __builtin_amdgcn_mfma_f32_16x16x32_f16(a1, wn[4 + kc], aNh1, 0, 0, 0);
        }

        // combine partials -> c_t, staging writes, xi
        unsigned sa = pkadd(pkadd(pkadd(u0a[0], u0a[1]), pkadd(u0a[2], u0a[3])),
                            pkadd(pkadd(u1a[0], u1a[1]), pkadd(u1a[2], u1a[3])));
        unsigned sb = pkadd(pkadd(pkadd(u0b[0], u0b[1]), pkadd(u0b[2], u0b[3])),
                            pkadd(pkadd(u1b[0], u1b[1]), pkadd(u1b[2], u1b[3])));
        const float c0 = tanh_f((float)h2(sa)[0] + cb);
        const float c1 = tanh_f((float)h2(sb)[0] + cb);
        if (wv == 0 && lane < 32) comp_sh[lane][t] = h16bits(lane < 16 ? c0 : c1);
        if (wv == 1 && lane < 32 && t > 0)
            pred_sh[lane][t - 1] = h16bits((float)h2(lane < 16 ? sa : sb)[1] + ob);

        const short xs0 = x_all[t][rA],      ms0 = m_all[t][rA];
        const short xs1 = x_all[t][16 + rA], ms1 = m_all[t][16 + rA];
        const _Float16 xi0 = ms0 ? __builtin_bit_cast(_Float16, xs0) : (_Float16)c0;
        const _Float16 xi1 = ms1 ? __builtin_bit_cast(_Float16, xs1) : (_Float16)c1;
        const half2_t xx0 = {xi0, xi0};
        const half2_t xx1 = {xi1, xi1};
        const half2_t z2 = {(_Float16)0, (_Float16)0};

        // feat chunks: build per chunk in regs, feed MFMAs immediately
#pragma unroll
        for (int kc = 0; kc < 4; ++kc) {
            uint4_t f0, f1;
#pragma unroll
            for (int p = 0; p < 4; ++p) {
                half2_t v0 = h2(wxp[kc * 4 + p]) * xx0 + h2(bxp[kc * 4 + p]);
                half2_t v1 = h2(wxp[kc * 4 + p]) * xx1 + h2(bxp[kc * 4 + p]);
                v0[0] = v0[0] > z2[0] ? v0[0] : z2[0];
                v0[1] = v0[1] > z2[0] ? v0[1] : z2[0];
                v1[0] = v1[0] > z2[0] ? v1[0] : z2[0];
                v1[1] = v1[1] > z2[0] ? v1[1] : z2[0];
                f0[p] = __builtin_bit_cast(unsigned, v0);
                f1[p] = __builtin_bit_cast(unsigned, v1);
            }
            half8 a0 = __builtin_bit_cast(half8, f0);
            half8 a1 = __builtin_bit_cast(half8, f1);
            aR0  = __builtin_amdgcn_mfma_f32_16x16x32_f16(a0, wr[kc], aR0, 0, 0, 0);
            aZ0  = __builtin_amdgcn_mfma_f32_16x16x32_f16(a0, wz[kc], aZ0, 0, 0, 0);
            aNi0 = __builtin_amdgcn_mfma_f32_16x16x32_f16(a0, wn[kc], aNi0, 0, 0, 0);
            aR1  = __builtin_amdgcn_mfma_f32_16x16x32_f16(a1, wr[kc], aR1, 0, 0, 0);
            aZ1  = __builtin_amdgcn_mfma_f32_16x16x32_f16(a1, wz[kc], aZ1, 0, 0, 0);
            aNi1 = __builtin_amdgcn_mfma_f32_16x16x32_f16(a1, wn[kc], aNi1, 0, 0, 0);
        }

        // gates + h update
        f32x4 hn0, hn1;
#pragma unroll
        for (int e = 0; e < 4; ++e) {
            const float hp0v = (e < 2) ? (float)h2(hpa0)[e & 1] : (float)h2(hpa1)[e & 1];
            const float hp1v = (e < 2) ? (float)h2(hpb0)[e & 1] : (float)h2(hpb1)[e & 1];
            float r = sigm(aR0[e]), z = sigm(aZ0[e]);
            float n = tanh_f(aNi0[e] + r * aNh0[e]);
            hn0[e] = z * (hp0v - n) + n;
            r = sigm(aR1[e]); z = sigm(aZ1[e]);
            n = tanh_f(aNi1[e] + r * aNh1[e]);
            hn1[e] = z * (hp1v - n) + n;
        }
        hpa0 = pk2(hn0[0], hn0[1]); hpa1 = pk2(hn0[2], hn0[3]);
        hpb0 = pk2(hn1[0], hn1[1]); hpb1 = pk2(hn1[2], hn1[3]);

        // write h frags (exactly the packed f16 values) into next buffer
        {
            const int fo = ((cH & 31) >> 3) * 128 + (cH & 7);
            short* d0 = &h_s[nb][0][cH >> 5][fo];
            short* d1 = &h_s[nb][1][cH >> 5][fo];
            d0[(rb + 0) * 8] = (short)(hpa0 & 0xffffu);
            d0[(rb + 1) * 8] = (short)(hpa0 >> 16);
            d0[(rb + 2) * 8] = (short)(hpa1 & 0xffffu);
            d0[(rb + 3) * 8] = (short)(hpa1 >> 16);
            d1[(rb + 0) * 8] = (short)(hpb0 & 0xffffu);
            d1[(rb + 1) * 8] = (short)(hpb0 >> 16);
            d1[(rb + 2) * 8] = (short)(hpb1 & 0xffffu);
            d1[(rb + 3) * 8] = (short)(hpb1 >> 16);
        }
        // fused (c,p) packed segmented reductions -> next partial buffer
#pragma unroll
        for (int e = 0; e < 4; ++e) {
            unsigned v0 = red16_pk(pk2(hn0[e] * wcc, hn0[e] * owc));
            unsigned v1 = red16_pk(pk2(hn1[e] * wcc, hn1[e] * owc));
            if (ln16 == 15) {
                part_cp[nb][rb + e][wv]      = v0;
                part_cp[nb][16 + rb + e][wv] = v1;
            }
        }
        __syncthreads();   // the single per-step barrier
    }

    // final pred from last partials (buffer 0 after t=255)
    {
        uint4_t u0a = *(const uint4_t*)&part_cp[0][rA][0];
        uint4_t u1a = *(const uint4_t*)&part_cp[0][rA][4];
        uint4_t u0b = *(const uint4_t*)&part_cp[0][16 + rA][0];
        uint4_t u1b = *(const uint4_t*)&part_cp[0][16 + rA][4];
        unsigned sa = pkadd(pkadd(pkadd(u0a[0], u0a[1]), pkadd(u0a[2], u0a[3])),
                            pkadd(pkadd(u1a[0], u1a[1]), pkadd(u1a[2], u1a[3])));
        unsigned sb = pkadd(pkadd(pkadd(u0b[0], u0b[1]), pkadd(u0b[2], u0b[3])),
                            pkadd(pkadd(u1b[0], u1b[1]), pkadd(u1b[2], u1b[3])));
        if (wv == 1 && lane < 32)
            pred_sh[lane][T_ - 1] = h16bits((float)h2(lane < 16 ? sa : sb)[1] + ob);
    }
    __syncthreads();

    // coalesced output: preds [0, B*T), comps [B*T, 2*B*T)
    {
        const int orow = tid >> 4;
        const int oc   = (tid & 15) * 16;
        short8_t p0 = *(const short8_t*)&pred_sh[orow][oc];
        short8_t p1 = *(const short8_t*)&pred_sh[orow][oc + 8];
        float* gp = out + (b0 + orow) * T_ + oc;
#pragma unroll
        for (int i = 0; i < 4; ++i) {
            f32x4 o;
            o[0] = h16f((i < 2) ? p0[i * 4 + 0] : p1[(i - 2) * 4 + 0]);
            o[1] = h16f((i < 2) ? p0[i * 4 + 1] : p1[(i - 2) * 4 + 1]);
            o[2] = h16f((i < 2) ? p0[i * 4 + 2] : p1[(i - 2) * 4 + 2]);
            o[3] = h16f((i < 2) ? p0[i * 4 + 3] : p1[(i - 2) * 4 + 3]);
            *(f32x4*)(gp + 4 * i) = o;
        }
        short8_t c0v = *(const short8_t*)&comp_sh[orow][oc];
        short8_t c1v = *(const short8_t*)&comp_sh[orow][oc + 8];
        float* gc = out + (long)B_ * T_ + (b0 + orow) * T_ + oc;
#pragma unroll
        for (int i = 0; i < 4; ++i) {
            f32x4 o;
            o[0] = h16f((i < 2) ? c0v[i * 4 + 0] : c1v[(i - 2) * 4 + 0]);
            o[1] = h16f((i < 2) ? c0v[i * 4 + 1] : c1v[(i - 2) * 4 + 1]);
            o[2] = h16f((i < 2) ? c0v[i * 4 + 2] : c1v[(i - 2) * 4 + 2]);
            o[3] = h16f((i < 2) ? c0v[i * 4 + 3] : c1v[(i - 2) * 4 + 3]);
            *(f32x4*)(gc + 4 * i) = o;
        }
    }
}

extern "C" void kernel_launch(void* const* d_in, const int* in_sizes, int n_in,
                              void* d_out, int out_size, void* d_ws, size_t ws_size,
                              hipStream_t stream) {
    const float* x_seq = (const float*)d_in[0];
    const float* m_seq = (const float*)d_in[1];
    const float* Wc_w  = (const float*)d_in[2];
    const float* Wc_b  = (const float*)d_in[3];
    const float* Wx_w  = (const float*)d_in[4];
    const float* Wx_b  = (const float*)d_in[5];
    const float* W_ih  = (const float*)d_in[6];
    const float* W_hh  = (const float*)d_in[7];
    const float* b_ih  = (const float*)d_in[8];
    const float* b_hh  = (const float*)d_in[9];
    const float* out_w = (const float*)d_in[10];
    const float* out_b = (const float*)d_in[11];
    float* out = (float*)d_out;

    dim3 grid(B_ / ROWS);   // 256 workgroups = 1 per CU, single round
    dim3 block(NTH);
    brits_kernel<<<grid, block, 0, stream>>>(x_seq, m_seq, Wc_w, Wc_b, Wx_w, Wx_b,
                                             W_ih, W_hh, b_ih, b_hh, out_w, out_b, out);
}